// Round 7
// baseline (399.162 us; speedup 1.0000x reference)
//
#include <hip/hip_runtime.h>
#include <stdint.h>

typedef unsigned short u16;
typedef __bf16 bf16x8 __attribute__((ext_vector_type(8)));
typedef float f32x4 __attribute__((ext_vector_type(4)));
typedef float f32x16 __attribute__((ext_vector_type(16)));

#define NB 2
#define NS 2048
#define NHID 2048
#define NHEAD 32
#define NKVH 8
#define DHEAD 64
#define MROWS (NB*NS)          // 4096
#define NQKV 3072              // 2048 Q + 512 K + 512 V
#define SCALE_LOG2E 0.18033688011112042f   // (1/8) * log2(e) — folded into Q at rope time

typedef const __attribute__((address_space(1))) unsigned int* gas1_t;
typedef __attribute__((address_space(3))) unsigned int* las3_t;
#define GLOAD16(gp, lp) __builtin_amdgcn_global_load_lds((gas1_t)(const void*)(gp), (las3_t)(void*)(lp), 16, 0, 0)

static __device__ __forceinline__ u16 f2bf(float f) {
  union { float f; unsigned u; } x; x.f = f;
  unsigned r = x.u + 0x7fffu + ((x.u >> 16) & 1u);
  return (u16)(r >> 16);
}
static __device__ __forceinline__ float bf2f(u16 h) {
  union { unsigned u; float f; } x; x.u = ((unsigned)h) << 16;
  return x.f;
}
static __device__ __forceinline__ bf16x8 as_bf16x8(uint4 v) {
  union { uint4 u; bf16x8 b; } x; x.u = v; return x.b;
}
static __device__ __forceinline__ unsigned cvtpk(float lo, float hi_) {
  unsigned r;
  asm("v_cvt_pk_bf16_f32 %0, %1, %2" : "=v"(r) : "v"(lo), "v"(hi_));
  return r;
}

// ---------------- fp32 -> bf16 cast (vectorized, 8 elems/thread) ----------------
__global__ __launch_bounds__(256) void cast_f32_to_bf16(
    const float* __restrict__ src, u16* __restrict__ dst, int n8) {
  int i = blockIdx.x * 256 + threadIdx.x;
  if (i >= n8) return;
  const float4* s = (const float4*)src;
  float4 a = s[2*i];
  float4 b = s[2*i+1];
  union { u16 us[8]; uint4 v; } o;
  o.us[0] = f2bf(a.x); o.us[1] = f2bf(a.y); o.us[2] = f2bf(a.z); o.us[3] = f2bf(a.w);
  o.us[4] = f2bf(b.x); o.us[5] = f2bf(b.y); o.us[6] = f2bf(b.z); o.us[7] = f2bf(b.w);
  ((uint4*)dst)[i] = o.v;
}

// ---------------- GEMM: C[M,N] = A[M,K] @ W[N,K]^T  (m97 structure) -------------
// 128x128 tile, BK=32, 4 waves (2x2), 16 MFMA 16x16x32 per wave per K-step.
// LDS linear [row][32], global_load_lds dbuf, single-barrier pipelined loop.
// 1D grid + XCD-aware bijective swizzle (T1; launches keep nwg % 8 == 0).
template<int OUT_F32>
__global__ __launch_bounds__(256) void gemm_bt(
    const u16* __restrict__ A, const u16* __restrict__ W, void* __restrict__ Cv,
    int M, int N, int K, int nxt) {
  __shared__ __align__(16) u16 As[2][128*32];
  __shared__ __align__(16) u16 Bs[2][128*32];
  const int cpx = gridDim.x >> 3;                  // blocks per XCD (nwg % 8 == 0)
  const int wgid = (blockIdx.x & 7) * cpx + (blockIdx.x >> 3);
  const int bx = wgid % nxt, by = wgid / nxt;
  const int t = threadIdx.x;
  const int lane = t & 63;
  const int w = t >> 6;
  const int wr = w >> 1, wc = w & 1;
  const int arow = lane & 15, kgrp = lane >> 4;
  const int m0 = by * 128, n0 = bx * 128;
  const int srow = lane >> 2, scol = lane & 3;
  const u16* Ag = A + (size_t)(m0 + 32*w + srow) * K + scol*8;
  const u16* Bg = W + (size_t)(n0 + 32*w + srow) * K + scol*8;

  f32x4 zero4 = {0.f, 0.f, 0.f, 0.f};
  f32x4 acc[4][4];
#pragma unroll
  for (int i = 0; i < 4; ++i)
#pragma unroll
    for (int j = 0; j < 4; ++j) acc[i][j] = zero4;

  // prologue: stage k-tile 0 into buf 0
  {
    u16* Ad = &As[0][0] + w*1024 + lane*8;
    u16* Bd = &Bs[0][0] + w*1024 + lane*8;
    GLOAD16(Ag, Ad);              GLOAD16(Ag + (size_t)16*K, Ad + 512);
    GLOAD16(Bg, Bd);              GLOAD16(Bg + (size_t)16*K, Bd + 512);
  }
  int cur = 0;
  for (int k0 = 0; k0 < K; k0 += 32) {
    __syncthreads();               // buf[cur] ready (vmcnt drained); buf[cur^1] free
    if (k0 + 32 < K) {
      u16* Ad = &As[cur^1][0] + w*1024 + lane*8;
      u16* Bd = &Bs[cur^1][0] + w*1024 + lane*8;
      GLOAD16(Ag + k0 + 32, Ad);            GLOAD16(Ag + (size_t)16*K + k0 + 32, Ad + 512);
      GLOAD16(Bg + k0 + 32, Bd);            GLOAD16(Bg + (size_t)16*K + k0 + 32, Bd + 512);
    }
    const u16* Asb = &As[cur][0];
    const u16* Bsb = &Bs[cur][0];
    bf16x8 af[4], bfr[4];
#pragma unroll
    for (int i = 0; i < 4; ++i) {
      int r = wr*64 + i*16 + arow;
      af[i] = as_bf16x8(*(const uint4*)(Asb + r*32 + kgrp*8));
    }
#pragma unroll
    for (int j = 0; j < 4; ++j) {
      int r = wc*64 + j*16 + arow;
      bfr[j] = as_bf16x8(*(const uint4*)(Bsb + r*32 + kgrp*8));
    }
#pragma unroll
    for (int i = 0; i < 4; ++i)
#pragma unroll
      for (int j = 0; j < 4; ++j)
        acc[i][j] = __builtin_amdgcn_mfma_f32_16x16x32_bf16(af[i], bfr[j], acc[i][j], 0, 0, 0);
    cur ^= 1;
  }
  // epilogue: D layout col = lane&15, row = (lane>>4)*4 + reg
#pragma unroll
  for (int i = 0; i < 4; ++i)
#pragma unroll
    for (int j = 0; j < 4; ++j)
#pragma unroll
      for (int r = 0; r < 4; ++r) {
        int row = m0 + wr*64 + i*16 + kgrp*4 + r;
        int col = n0 + wc*64 + j*16 + arow;
        if (OUT_F32) ((float*)Cv)[(size_t)row*N + col] = acc[i][j][r];
        else         ((u16*)Cv)[(size_t)row*N + col]  = f2bf(acc[i][j][r]);
      }
}

// ---------------- RoPE (vectorized): qkv -> qr [b,h,s,64], kr [b,kvh,s,64] -----
// Q additionally pre-scaled by SCALE*log2(e) so attn's softmax skips the mul.
__global__ __launch_bounds__(256) void rope_qk(
    const u16* __restrict__ qkv, const float* __restrict__ cosb, const float* __restrict__ sinb,
    u16* __restrict__ qr, u16* __restrict__ kr) {
  const int row = blockIdx.x;          // b*S + s
  const int b = row >> 11;
  const int s = row & (NS - 1);
  const u16* in = qkv + (size_t)row * NQKV;
  const float* cp = cosb + (size_t)row * DHEAD;
  const float* sp = sinb + (size_t)row * DHEAD;
  for (int e8 = threadIdx.x; e8 < 320; e8 += 256) {
    int e  = e8 * 8;
    int d0 = e & 63;
    uint4 vo = *(const uint4*)(in + e);
    uint4 vp = *(const uint4*)(in + (e ^ 32));
    float4 c0 = *(const float4*)(cp + d0);
    float4 c1 = *(const float4*)(cp + d0 + 4);
    float4 s0 = *(const float4*)(sp + d0);
    float4 s1 = *(const float4*)(sp + d0 + 4);
    float sgn = (d0 < 32) ? -1.f : 1.f;
    float cc[8] = {c0.x,c0.y,c0.z,c0.w,c1.x,c1.y,c1.z,c1.w};
    float ss[8] = {s0.x,s0.y,s0.z,s0.w,s1.x,s1.y,s1.z,s1.w};
    union { uint4 v; u16 us[8]; } a, p, o;
    a.v = vo; p.v = vp;
    float qs = (e < 2048) ? SCALE_LOG2E : 1.0f;
#pragma unroll
    for (int j = 0; j < 8; ++j)
      o.us[j] = f2bf((bf2f(a.us[j])*cc[j] + sgn*bf2f(p.us[j])*ss[j]) * qs);
    if (e < 2048) {
      int hh = e >> 6;
      *(uint4*)(qr + (((size_t)b*NHEAD + hh)*NS + s)*DHEAD + d0) = o.v;
    } else {
      int kh = (e - 2048) >> 6;
      *(uint4*)(kr + (((size_t)b*NKVH + kh)*NS + s)*DHEAD + d0) = o.v;
    }
  }
}

// ---------------- V transpose: qkv[.,2560+kh*64+d] -> vt [b,kvh,d,S] ------------
__global__ __launch_bounds__(256) void v_trans(const u16* __restrict__ qkv, u16* __restrict__ vt) {
  __shared__ __align__(16) u16 tile[64][72];
  const int st = blockIdx.x & 31, kh = (blockIdx.x >> 5) & 7, b = blockIdx.x >> 8;
  const int s0 = st * 64;
  const int t = threadIdx.x;
#pragma unroll
  for (int it = 0; it < 2; ++it) {
    int r = (t >> 3) + 32*it;
    int c = t & 7;
    uint4 v = *(const uint4*)(qkv + (size_t)(b*NS + s0 + r)*NQKV + 2560 + kh*64 + c*8);
    *(uint4*)(&tile[r][c*8]) = v;
  }
  __syncthreads();
#pragma unroll
  for (int it = 0; it < 2; ++it) {
    int d = (t >> 3) + 32*it;
    int c = t & 7;
    union { uint4 v; u16 us[8]; } o;
#pragma unroll
    for (int j = 0; j < 8; ++j) o.us[j] = tile[c*8 + j][d];
    *(uint4*)(vt + ((size_t)(b*NKVH + kh)*DHEAD + d)*NS + s0 + c*8) = o.v;
  }
}

// ---------------- causal GQA flash attention (32x32 swapped-operand) -----------
// grid (16, NH, B) = 1024 blocks, UNPAIRED q-tiles: qt = 15 - blockIdx.x so the
// biggest tiles (T = 2*qt+2 KV-iters) dispatch first (LPT makespan). 4 waves x
// 32 q-rows = QBLK 128. S^T = mfma(K, Q); O^T = mfma(V^T, P^T): softmax state
// per-lane (q = lane&31). K/V LDS rows 128B XOR-swizzled chunk^(row&7) via
// pre-swizzled global source + global_load_lds (dbuf, single barrier/iter).
__global__ __launch_bounds__(256) void attn_fwd(
    const u16* __restrict__ qr, const u16* __restrict__ kr, const u16* __restrict__ vt,
    u16* __restrict__ ao) {
  __shared__ __align__(16) u16 lds[2][2][64*64];   // [buf][K/V][..] = 32 KiB
  const int qt = 15 - blockIdx.x, h = blockIdx.y, b = blockIdx.z;
  const int kvh = h >> 2;                           // N_REP = 4
  const int t = threadIdx.x, lane = t & 63, w = t >> 6;
  const int q31 = lane & 31, hi = lane >> 5;
  const u16* Qb = qr + ((size_t)b*NHEAD + h) * NS * DHEAD;
  const u16* Kb = kr + ((size_t)b*NKVH + kvh) * NS * DHEAD;
  const u16* Vb = vt + ((size_t)b*NKVH + kvh) * DHEAD * NS;
  const int sgc = (lane & 7) ^ (lane >> 3);         // pre-swizzled global 16B chunk

  const int q0 = qt * 128;
  const int qmin = q0 + w*32;
  const int T = 2*qt + 2;

  // Q fragments (B-operand): lane q31 reads its q-row directly from global
  bf16x8 qf[4];
  const u16* qrow = Qb + (size_t)(qmin + q31)*DHEAD + hi*8;
#pragma unroll
  for (int kt = 0; kt < 4; ++kt)
    qf[kt] = as_bf16x8(*(const uint4*)(qrow + kt*16));

  f32x16 oacc[2];
#pragma unroll
  for (int r = 0; r < 16; ++r) { oacc[0][r] = 0.f; oacc[1][r] = 0.f; }
  float m = -3.0e38f, l = 0.f;

  {  // stage tile 0 -> buf 0
    u16* Kd = &lds[0][0][0] + w*1024 + lane*8;
    u16* Vd = &lds[0][1][0] + w*1024 + lane*8;
    const u16* Kg = Kb + (size_t)(16*w + (lane>>3))*DHEAD + sgc*8;
    const u16* Vg = Vb + (size_t)(16*w + (lane>>3))*NS + sgc*8;
    GLOAD16(Kg, Kd);  GLOAD16(Kg + 8*DHEAD, Kd + 512);
    GLOAD16(Vg, Vd);  GLOAD16(Vg + 8*NS,    Vd + 512);
  }
  int cur = 0;
  for (int kb = 0; kb < T; ++kb) {
    __syncthreads();             // buf[cur] ready; buf[cur^1] free
    if (kb + 1 < T) {
      const int kv1 = (kb + 1) * 64;
      u16* Kd = &lds[cur^1][0][0] + w*1024 + lane*8;
      u16* Vd = &lds[cur^1][1][0] + w*1024 + lane*8;
      const u16* Kg = Kb + (size_t)(kv1 + 16*w + (lane>>3))*DHEAD + sgc*8;
      const u16* Vg = Vb + (size_t)(16*w + (lane>>3))*NS + kv1 + sgc*8;
      GLOAD16(Kg, Kd);  GLOAD16(Kg + 8*DHEAD, Kd + 512);
      GLOAD16(Vg, Vd);  GLOAD16(Vg + 8*NS,    Vd + 512);
    }
    const int kv0 = kb * 64;
    if (kv0 <= qmin + 31) {      // wave-uniform activity predicate
      const u16* Ksb = &lds[cur][0][0];
      const u16* Vsb = &lds[cur][1][0];
      // ---- S^T = K @ Q^T : 2 tiles (kv halves) x 4 k-slices ----
      f32x16 sacc[2];
#pragma unroll
      for (int r = 0; r < 16; ++r) { sacc[0][r] = 0.f; sacc[1][r] = 0.f; }
#pragma unroll
      for (int kvt = 0; kvt < 2; ++kvt) {
        int kv = kvt*32 + q31;
#pragma unroll
        for (int kt = 0; kt < 4; ++kt) {
          int phys = (2*kt + hi) ^ (kv & 7);
          bf16x8 ka = as_bf16x8(*(const uint4*)(Ksb + kv*64 + phys*8));
          sacc[kvt] = __builtin_amdgcn_mfma_f32_32x32x16_bf16(ka, qf[kt], sacc[kvt], 0, 0, 0);
        }
      }
      // ---- softmax (exp2 domain; Q pre-scaled), state per-lane: q = lane&31 ----
      const bool diag = (kv0 + 63 > qmin);
      const int qa = qmin + q31;
      float x[2][16];
      float pmq[4] = {-3.0e38f, -3.0e38f, -3.0e38f, -3.0e38f};
#pragma unroll
      for (int kvt = 0; kvt < 2; ++kvt)
#pragma unroll
        for (int r = 0; r < 16; ++r) {
          float sv = sacc[kvt][r];
          if (diag) {
            int kva = kv0 + kvt*32 + 8*(r>>2) + 4*hi + (r&3);
            sv = (kva > qa) ? -3.0e38f : sv;
          }
          x[kvt][r] = sv;
          pmq[r & 3] = fmaxf(pmq[r & 3], sv);
        }
      float pm = fmaxf(fmaxf(pmq[0], pmq[1]), fmaxf(pmq[2], pmq[3]));
      pm = fmaxf(pm, __shfl_xor(pm, 32));
      if (!__all(pm <= m + 8.0f)) {          // defer-max (THR=8)
        float mn = fmaxf(m, pm);
        float al = __builtin_amdgcn_exp2f(m - mn);
        l *= al;
#pragma unroll
        for (int r = 0; r < 16; ++r) { oacc[0][r] *= al; oacc[1][r] *= al; }
        m = mn;
      }
      float sq[4] = {0.f, 0.f, 0.f, 0.f};
#pragma unroll
      for (int kvt = 0; kvt < 2; ++kvt)
#pragma unroll
        for (int r = 0; r < 16; ++r) {
          float pv = __builtin_amdgcn_exp2f(x[kvt][r] - m);
          x[kvt][r] = pv;
          sq[r & 3] += pv;
        }
      float rs = (sq[0] + sq[1]) + (sq[2] + sq[3]);
      rs += __shfl_xor(rs, 32);
      l += rs;
      // ---- pack P -> bf16 pairs; exchange halves with lane^32 ----
      unsigned own[2][4][2];
#pragma unroll
      for (int kvt = 0; kvt < 2; ++kvt)
#pragma unroll
        for (int c = 0; c < 4; ++c) {
          own[kvt][c][0] = cvtpk(x[kvt][4*c+0], x[kvt][4*c+1]);
          own[kvt][c][1] = cvtpk(x[kvt][4*c+2], x[kvt][4*c+3]);
        }
      unsigned ex[2][2][2];
#pragma unroll
      for (int kvt = 0; kvt < 2; ++kvt)
#pragma unroll
        for (int s = 0; s < 2; ++s)
#pragma unroll
          for (int wd = 0; wd < 2; ++wd) {
            unsigned snd = hi ? own[kvt][2*s][wd] : own[kvt][2*s+1][wd];
            ex[kvt][s][wd] = (unsigned)__shfl_xor((int)snd, 32);
          }
      // ---- build P^T B-frags (4 k-slices of 16 kv) ----
      bf16x8 pb[4];
#pragma unroll
      for (int ks = 0; ks < 4; ++ks) {
        int kvt = ks >> 1, s = ks & 1;
        unsigned L0 = hi ? ex[kvt][s][0]      : own[kvt][2*s][0];
        unsigned L1 = hi ? ex[kvt][s][1]      : own[kvt][2*s][1];
        unsigned H0 = hi ? own[kvt][2*s+1][0] : ex[kvt][s][0];
        unsigned H1 = hi ? own[kvt][2*s+1][1] : ex[kvt][s][1];
        uint4 u = {L0, L1, H0, H1};
        pb[ks] = as_bf16x8(u);
      }
      // ---- O^T += V^T @ P^T ----
#pragma unroll
      for (int dt = 0; dt < 2; ++dt) {
        int d = dt*32 + q31;
#pragma unroll
        for (int ks = 0; ks < 4; ++ks) {
          int phys = (2*ks + hi) ^ (d & 7);
          bf16x8 va = as_bf16x8(*(const uint4*)(Vsb + d*64 + phys*8));
          oacc[dt] = __builtin_amdgcn_mfma_f32_32x32x16_bf16(va, pb[ks], oacc[dt], 0, 0, 0);
        }
      }
    }
    cur ^= 1;
  }
  // ---- epilogue: O^T/l -> per-wave LDS [32 q][64 d] (swizzled) -> coalesced ao
  float inv = 1.0f / l;
  u16* ep = &lds[0][0][0] + w*2048;     // buf0 free: T even, last prefetch went to buf1
#pragma unroll
  for (int dt = 0; dt < 2; ++dt)
#pragma unroll
    for (int c = 0; c < 4; ++c) {
      unsigned w0 = cvtpk(oacc[dt][4*c+0]*inv, oacc[dt][4*c+1]*inv);
      unsigned w1 = cvtpk(oacc[dt][4*c+2]*inv, oacc[dt][4*c+3]*inv);
      int colb = dt*64 + c*16 + hi*8;   // byte col of d-base
      int addrb = q31*128 + (colb ^ ((q31 & 7) << 4));
      *(uint2*)((char*)ep + addrb) = make_uint2(w0, w1);
    }
#pragma unroll
  for (int it = 0; it < 4; ++it) {
    int r  = (lane >> 3) + 8*it;
    int c8 = lane & 7;
    int phys = (c8*16) ^ ((r & 7) << 4);
    uint4 vv = *(const uint4*)((const char*)ep + r*128 + phys);
    *(uint4*)(ao + ((size_t)b*NS + q0 + w*32 + r)*(size_t)(NHEAD*DHEAD) + h*DHEAD + c8*8) = vv;
  }
}

// ---------------- launch -----------------------------------------------------
// Workspace (63 MB, lifetime-aliased):
//   [0,16M)       hb (bf16 hidden)  -> reused as qr
//   [16M,29.4M)   wqkv              -> reused as kr (4M) + vt (4M @20.97M)
//   [29.4M,54.5M) qkv               -> reused as ao
//   [54.5M,62.9M) wob
extern "C" void kernel_launch(void* const* d_in, const int* in_sizes, int n_in,
                              void* d_out, int out_size, void* d_ws, size_t ws_size,
                              hipStream_t stream) {
  const float* hs   = (const float*)d_in[0];
  const float* cosb = (const float*)d_in[1];
  const float* sinb = (const float*)d_in[2];
  // d_in[3] = attention_mask: exactly causal -> applied analytically, never read
  const float* Wq = (const float*)d_in[4];
  const float* Wk = (const float*)d_in[5];
  const float* Wv = (const float*)d_in[6];
  const float* Wo = (const float*)d_in[7];
  char* ws = (char*)d_ws;
  u16* hb   = (u16*)(ws);
  u16* wqkv = (u16*)(ws + 16777216);
  u16* qkv  = (u16*)(ws + 29360128);
  u16* wob  = (u16*)(ws + 54525952);
  u16* qrb  = hb;
  u16* krb  = wqkv;
  u16* vtb  = (u16*)(ws + 20971520);
  u16* aob  = qkv;

  cast_f32_to_bf16<<<4096, 256, 0, stream>>>(hs, hb, 1048576);
  cast_f32_to_bf16<<<2048, 256, 0, stream>>>(Wq, wqkv, 524288);
  cast_f32_to_bf16<<< 512, 256, 0, stream>>>(Wk, wqkv + 2048*2048, 131072);
  cast_f32_to_bf16<<< 512, 256, 0, stream>>>(Wv, wqkv + 2560*2048, 131072);
  cast_f32_to_bf16<<<2048, 256, 0, stream>>>(Wo, wob, 524288);

  gemm_bt<0><<<(NQKV/128)*(MROWS/128), 256, 0, stream>>>(hb, wqkv, qkv, MROWS, NQKV, NHID, NQKV/128);
  rope_qk<<<MROWS, 256, 0, stream>>>(qkv, cosb, sinb, qrb, krb);
  v_trans<<<512, 256, 0, stream>>>(qkv, vtb);
  attn_fwd<<<dim3(16, NHEAD, NB), 256, 0, stream>>>(qrb, krb, vtb, aob);
  gemm_bt<1><<<(NHID/128)*(MROWS/128), 256, 0, stream>>>(aob, wob, d_out, MROWS, NHID, NHEAD*DHEAD, NHID/128);
}

// Round 9
// 345.018 us; speedup vs baseline: 1.1569x; 1.1569x over previous
//
#include <hip/hip_runtime.h>
#include <stdint.h>

typedef unsigned short u16;
typedef __bf16 bf16x8 __attribute__((ext_vector_type(8)));
typedef float f32x4 __attribute__((ext_vector_type(4)));
typedef float f32x16 __attribute__((ext_vector_type(16)));

#define NB 2
#define NS 2048
#define NHID 2048
#define NHEAD 32
#define NKVH 8
#define DHEAD 64
#define MROWS (NB*NS)          // 4096
#define NQKV 3072              // 2048 Q + 512 K + 512 V
#define SCALE_LOG2E 0.18033688011112042f   // (1/8) * log2(e) — folded into Q at rope time

typedef const __attribute__((address_space(1))) unsigned int* gas1_t;
typedef __attribute__((address_space(3))) unsigned int* las3_t;
#define GLOAD16(gp, lp) __builtin_amdgcn_global_load_lds((gas1_t)(const void*)(gp), (las3_t)(void*)(lp), 16, 0, 0)

static __device__ __forceinline__ u16 f2bf(float f) {
  union { float f; unsigned u; } x; x.f = f;
  unsigned r = x.u + 0x7fffu + ((x.u >> 16) & 1u);
  return (u16)(r >> 16);
}
static __device__ __forceinline__ float bf2f(u16 h) {
  union { unsigned u; float f; } x; x.u = ((unsigned)h) << 16;
  return x.f;
}
static __device__ __forceinline__ bf16x8 as_bf16x8(uint4 v) {
  union { uint4 u; bf16x8 b; } x; x.u = v; return x.b;
}
static __device__ __forceinline__ unsigned cvtpk(float lo, float hi_) {
  unsigned r;
  asm("v_cvt_pk_bf16_f32 %0, %1, %2" : "=v"(r) : "v"(lo), "v"(hi_));
  return r;
}

// ---------------- fp32 -> bf16 cast (vectorized, 8 elems/thread) ----------------
__global__ __launch_bounds__(256) void cast_f32_to_bf16(
    const float* __restrict__ src, u16* __restrict__ dst, int n8) {
  int i = blockIdx.x * 256 + threadIdx.x;
  if (i >= n8) return;
  const float4* s = (const float4*)src;
  float4 a = s[2*i];
  float4 b = s[2*i+1];
  union { u16 us[8]; uint4 v; } o;
  o.us[0] = f2bf(a.x); o.us[1] = f2bf(a.y); o.us[2] = f2bf(a.z); o.us[3] = f2bf(a.w);
  o.us[4] = f2bf(b.x); o.us[5] = f2bf(b.y); o.us[6] = f2bf(b.z); o.us[7] = f2bf(b.w);
  ((uint4*)dst)[i] = o.v;
}

// ---------------- GEMM: C[M,N] = A[M,K] @ W[N,K]^T  (m97 structure) -------------
// 128x128 tile, BK=32, 4 waves (2x2), 16 MFMA 16x16x32 per wave per K-step.
// LDS linear [row][32], global_load_lds dbuf, single-barrier pipelined loop.
// 1D grid + XCD-aware bijective swizzle (T1; launches keep nwg % 8 == 0).
template<int OUT_F32>
__global__ __launch_bounds__(256) void gemm_bt(
    const u16* __restrict__ A, const u16* __restrict__ W, void* __restrict__ Cv,
    int M, int N, int K, int nxt) {
  __shared__ __align__(16) u16 As[2][128*32];
  __shared__ __align__(16) u16 Bs[2][128*32];
  const int cpx = gridDim.x >> 3;                  // blocks per XCD (nwg % 8 == 0)
  const int wgid = (blockIdx.x & 7) * cpx + (blockIdx.x >> 3);
  const int bx = wgid % nxt, by = wgid / nxt;
  const int t = threadIdx.x;
  const int lane = t & 63;
  const int w = t >> 6;
  const int wr = w >> 1, wc = w & 1;
  const int arow = lane & 15, kgrp = lane >> 4;
  const int m0 = by * 128, n0 = bx * 128;
  const int srow = lane >> 2, scol = lane & 3;
  const u16* Ag = A + (size_t)(m0 + 32*w + srow) * K + scol*8;
  const u16* Bg = W + (size_t)(n0 + 32*w + srow) * K + scol*8;

  f32x4 zero4 = {0.f, 0.f, 0.f, 0.f};
  f32x4 acc[4][4];
#pragma unroll
  for (int i = 0; i < 4; ++i)
#pragma unroll
    for (int j = 0; j < 4; ++j) acc[i][j] = zero4;

  // prologue: stage k-tile 0 into buf 0
  {
    u16* Ad = &As[0][0] + w*1024 + lane*8;
    u16* Bd = &Bs[0][0] + w*1024 + lane*8;
    GLOAD16(Ag, Ad);              GLOAD16(Ag + (size_t)16*K, Ad + 512);
    GLOAD16(Bg, Bd);              GLOAD16(Bg + (size_t)16*K, Bd + 512);
  }
  int cur = 0;
  for (int k0 = 0; k0 < K; k0 += 32) {
    __syncthreads();               // buf[cur] ready (vmcnt drained); buf[cur^1] free
    if (k0 + 32 < K) {
      u16* Ad = &As[cur^1][0] + w*1024 + lane*8;
      u16* Bd = &Bs[cur^1][0] + w*1024 + lane*8;
      GLOAD16(Ag + k0 + 32, Ad);            GLOAD16(Ag + (size_t)16*K + k0 + 32, Ad + 512);
      GLOAD16(Bg + k0 + 32, Bd);            GLOAD16(Bg + (size_t)16*K + k0 + 32, Bd + 512);
    }
    const u16* Asb = &As[cur][0];
    const u16* Bsb = &Bs[cur][0];
    bf16x8 af[4], bfr[4];
#pragma unroll
    for (int i = 0; i < 4; ++i) {
      int r = wr*64 + i*16 + arow;
      af[i] = as_bf16x8(*(const uint4*)(Asb + r*32 + kgrp*8));
    }
#pragma unroll
    for (int j = 0; j < 4; ++j) {
      int r = wc*64 + j*16 + arow;
      bfr[j] = as_bf16x8(*(const uint4*)(Bsb + r*32 + kgrp*8));
    }
#pragma unroll
    for (int i = 0; i < 4; ++i)
#pragma unroll
      for (int j = 0; j < 4; ++j)
        acc[i][j] = __builtin_amdgcn_mfma_f32_16x16x32_bf16(af[i], bfr[j], acc[i][j], 0, 0, 0);
    cur ^= 1;
  }
  // epilogue: D layout col = lane&15, row = (lane>>4)*4 + reg
#pragma unroll
  for (int i = 0; i < 4; ++i)
#pragma unroll
    for (int j = 0; j < 4; ++j)
#pragma unroll
      for (int r = 0; r < 4; ++r) {
        int row = m0 + wr*64 + i*16 + kgrp*4 + r;
        int col = n0 + wc*64 + j*16 + arow;
        if (OUT_F32) ((float*)Cv)[(size_t)row*N + col] = acc[i][j][r];
        else         ((u16*)Cv)[(size_t)row*N + col]  = f2bf(acc[i][j][r]);
      }
}

// ---------------- RoPE (vectorized): qkv -> qr [b,h,s,64], kr [b,kvh,s,64] -----
// Q additionally pre-scaled by SCALE*log2(e) so attn's softmax skips the mul.
__global__ __launch_bounds__(256) void rope_qk(
    const u16* __restrict__ qkv, const float* __restrict__ cosb, const float* __restrict__ sinb,
    u16* __restrict__ qr, u16* __restrict__ kr) {
  const int row = blockIdx.x;          // b*S + s
  const int b = row >> 11;
  const int s = row & (NS - 1);
  const u16* in = qkv + (size_t)row * NQKV;
  const float* cp = cosb + (size_t)row * DHEAD;
  const float* sp = sinb + (size_t)row * DHEAD;
  for (int e8 = threadIdx.x; e8 < 320; e8 += 256) {
    int e  = e8 * 8;
    int d0 = e & 63;
    uint4 vo = *(const uint4*)(in + e);
    uint4 vp = *(const uint4*)(in + (e ^ 32));
    float4 c0 = *(const float4*)(cp + d0);
    float4 c1 = *(const float4*)(cp + d0 + 4);
    float4 s0 = *(const float4*)(sp + d0);
    float4 s1 = *(const float4*)(sp + d0 + 4);
    float sgn = (d0 < 32) ? -1.f : 1.f;
    float cc[8] = {c0.x,c0.y,c0.z,c0.w,c1.x,c1.y,c1.z,c1.w};
    float ss[8] = {s0.x,s0.y,s0.z,s0.w,s1.x,s1.y,s1.z,s1.w};
    union { uint4 v; u16 us[8]; } a, p, o;
    a.v = vo; p.v = vp;
    float qs = (e < 2048) ? SCALE_LOG2E : 1.0f;
#pragma unroll
    for (int j = 0; j < 8; ++j)
      o.us[j] = f2bf((bf2f(a.us[j])*cc[j] + sgn*bf2f(p.us[j])*ss[j]) * qs);
    if (e < 2048) {
      int hh = e >> 6;
      *(uint4*)(qr + (((size_t)b*NHEAD + hh)*NS + s)*DHEAD + d0) = o.v;
    } else {
      int kh = (e - 2048) >> 6;
      *(uint4*)(kr + (((size_t)b*NKVH + kh)*NS + s)*DHEAD + d0) = o.v;
    }
  }
}

// ---------------- V transpose: qkv[.,2560+kh*64+d] -> vt [b,kvh,d,S] ------------
__global__ __launch_bounds__(256) void v_trans(const u16* __restrict__ qkv, u16* __restrict__ vt) {
  __shared__ __align__(16) u16 tile[64][72];
  const int st = blockIdx.x & 31, kh = (blockIdx.x >> 5) & 7, b = blockIdx.x >> 8;
  const int s0 = st * 64;
  const int t = threadIdx.x;
#pragma unroll
  for (int it = 0; it < 2; ++it) {
    int r = (t >> 3) + 32*it;
    int c = t & 7;
    uint4 v = *(const uint4*)(qkv + (size_t)(b*NS + s0 + r)*NQKV + 2560 + kh*64 + c*8);
    *(uint4*)(&tile[r][c*8]) = v;
  }
  __syncthreads();
#pragma unroll
  for (int it = 0; it < 2; ++it) {
    int d = (t >> 3) + 32*it;
    int c = t & 7;
    union { uint4 v; u16 us[8]; } o;
#pragma unroll
    for (int j = 0; j < 8; ++j) o.us[j] = tile[c*8 + j][d];
    *(uint4*)(vt + ((size_t)(b*NKVH + kh)*DHEAD + d)*NS + s0 + c*8) = o.v;
  }
}

// ---------------- causal GQA flash attention (32x32 swapped-operand) -----------
// 1D grid of 1024 blocks with CO-RESIDENCY-BALANCED size mapping:
//   n = k*256 + r; s = r&7, j = r>>3;
//   qt = {k0: 2s, k1: 15-2s, k2: 2s+1, k3: 14-2s};  hb = j + 32*(k&1)
// Bijective onto (qt, h, b). Co-resident blocks on a CU are spaced ~256 in
// dispatch ID (same r, k=0..3): their T = {4s+2, 32-4s, 4s+4, 30-4s} sums to 68
// for EVERY CU — fixes R7's aliasing pathology (same-x blocks clustering on a
// CU) while keeping 1024 blocks = 16 waves/CU for VALU stall-filling.
// S^T = mfma(K, Q); O^T = mfma(V^T, P^T): softmax state per-lane (q = lane&31).
// K/V LDS rows 128B XOR-swizzled chunk^(row&7) via pre-swizzled global source +
// global_load_lds (dbuf, single barrier/iter).
__global__ __launch_bounds__(256) void attn_fwd(
    const u16* __restrict__ qr, const u16* __restrict__ kr, const u16* __restrict__ vt,
    u16* __restrict__ ao) {
  __shared__ __align__(16) u16 lds[2][2][64*64];   // [buf][K/V][..] = 32 KiB
  const int n = blockIdx.x;
  const int k = n >> 8, r5 = n & 255;
  const int s5 = r5 & 7, j5 = r5 >> 3;
  const int qt = (k == 0) ? 2*s5 : (k == 1) ? 15 - 2*s5 : (k == 2) ? 2*s5 + 1 : 14 - 2*s5;
  const int hb = j5 + ((k & 1) << 5);
  const int h = hb & 31, b = hb >> 5;
  const int kvh = h >> 2;                           // N_REP = 4
  const int t = threadIdx.x, lane = t & 63, w = t >> 6;
  const int q31 = lane & 31, hi = lane >> 5;
  const u16* Qb = qr + ((size_t)b*NHEAD + h) * NS * DHEAD;
  const u16* Kb = kr + ((size_t)b*NKVH + kvh) * NS * DHEAD;
  const u16* Vb = vt + ((size_t)b*NKVH + kvh) * DHEAD * NS;
  const int sgc = (lane & 7) ^ (lane >> 3);         // pre-swizzled global 16B chunk

  const int q0 = qt * 128;
  const int qmin = q0 + w*32;
  const int T = 2*qt + 2;

  // Q fragments (B-operand): lane q31 reads its q-row directly from global
  bf16x8 qf[4];
  const u16* qrow = Qb + (size_t)(qmin + q31)*DHEAD + hi*8;
#pragma unroll
  for (int kt = 0; kt < 4; ++kt)
    qf[kt] = as_bf16x8(*(const uint4*)(qrow + kt*16));

  f32x16 zero16;
#pragma unroll
  for (int r = 0; r < 16; ++r) zero16[r] = 0.f;    // persistent zero C-operand
  f32x16 oacc[2];
  oacc[0] = zero16; oacc[1] = zero16;
  float m = -3.0e38f, l = 0.f;

  {  // stage tile 0 -> buf 0
    u16* Kd = &lds[0][0][0] + w*1024 + lane*8;
    u16* Vd = &lds[0][1][0] + w*1024 + lane*8;
    const u16* Kg = Kb + (size_t)(16*w + (lane>>3))*DHEAD + sgc*8;
    const u16* Vg = Vb + (size_t)(16*w + (lane>>3))*NS + sgc*8;
    GLOAD16(Kg, Kd);  GLOAD16(Kg + 8*DHEAD, Kd + 512);
    GLOAD16(Vg, Vd);  GLOAD16(Vg + 8*NS,    Vd + 512);
  }
  int cur = 0;
  for (int kb = 0; kb < T; ++kb) {
    __syncthreads();             // buf[cur] ready; buf[cur^1] free
    if (kb + 1 < T) {
      const int kv1 = (kb + 1) * 64;
      u16* Kd = &lds[cur^1][0][0] + w*1024 + lane*8;
      u16* Vd = &lds[cur^1][1][0] + w*1024 + lane*8;
      const u16* Kg = Kb + (size_t)(kv1 + 16*w + (lane>>3))*DHEAD + sgc*8;
      const u16* Vg = Vb + (size_t)(16*w + (lane>>3))*NS + kv1 + sgc*8;
      GLOAD16(Kg, Kd);  GLOAD16(Kg + 8*DHEAD, Kd + 512);
      GLOAD16(Vg, Vd);  GLOAD16(Vg + 8*NS,    Vd + 512);
    }
    const int kv0 = kb * 64;
    if (kv0 <= qmin + 31) {      // wave-uniform activity predicate
      const u16* Ksb = &lds[cur][0][0];
      const u16* Vsb = &lds[cur][1][0];
      // ---- S^T = K @ Q^T : 2 tiles (kv halves) x 4 k-slices; C0 = zero16 ----
      f32x16 sacc[2];
#pragma unroll
      for (int kvt = 0; kvt < 2; ++kvt) {
        int kv = kvt*32 + q31;
        {
          int phys = hi ^ (kv & 7);
          bf16x8 ka = as_bf16x8(*(const uint4*)(Ksb + kv*64 + phys*8));
          sacc[kvt] = __builtin_amdgcn_mfma_f32_32x32x16_bf16(ka, qf[0], zero16, 0, 0, 0);
        }
#pragma unroll
        for (int kt = 1; kt < 4; ++kt) {
          int phys = (2*kt + hi) ^ (kv & 7);
          bf16x8 ka = as_bf16x8(*(const uint4*)(Ksb + kv*64 + phys*8));
          sacc[kvt] = __builtin_amdgcn_mfma_f32_32x32x16_bf16(ka, qf[kt], sacc[kvt], 0, 0, 0);
        }
      }
      // ---- softmax (exp2 domain; Q pre-scaled), state per-lane: q = lane&31 ----
      const bool diag = (kv0 + 63 > qmin);
      const int qa = qmin + q31;
      float x[2][16];
      float pmq[4] = {-3.0e38f, -3.0e38f, -3.0e38f, -3.0e38f};
#pragma unroll
      for (int kvt = 0; kvt < 2; ++kvt)
#pragma unroll
        for (int r = 0; r < 16; ++r) {
          float sv = sacc[kvt][r];
          if (diag) {
            int kva = kv0 + kvt*32 + 8*(r>>2) + 4*hi + (r&3);
            sv = (kva > qa) ? -3.0e38f : sv;
          }
          x[kvt][r] = sv;
          pmq[r & 3] = fmaxf(pmq[r & 3], sv);
        }
      float pm = fmaxf(fmaxf(pmq[0], pmq[1]), fmaxf(pmq[2], pmq[3]));
      pm = fmaxf(pm, __shfl_xor(pm, 32));
      if (!__all(pm <= m + 8.0f)) {          // defer-max (THR=8)
        float mn = fmaxf(m, pm);
        float al = __builtin_amdgcn_exp2f(m - mn);
        l *= al;
#pragma unroll
        for (int r = 0; r < 16; ++r) { oacc[0][r] *= al; oacc[1][r] *= al; }
        m = mn;
      }
      float sq[4] = {0.f, 0.f, 0.f, 0.f};
#pragma unroll
      for (int kvt = 0; kvt < 2; ++kvt)
#pragma unroll
        for (int r = 0; r < 16; ++r) {
          float pv = __builtin_amdgcn_exp2f(x[kvt][r] - m);
          x[kvt][r] = pv;
          sq[r & 3] += pv;
        }
      float rs = (sq[0] + sq[1]) + (sq[2] + sq[3]);
      rs += __shfl_xor(rs, 32);
      l += rs;
      // ---- pack P -> bf16 pairs; exchange halves with lane^32 ----
      unsigned own[2][4][2];
#pragma unroll
      for (int kvt = 0; kvt < 2; ++kvt)
#pragma unroll
        for (int c = 0; c < 4; ++c) {
          own[kvt][c][0] = cvtpk(x[kvt][4*c+0], x[kvt][4*c+1]);
          own[kvt][c][1] = cvtpk(x[kvt][4*c+2], x[kvt][4*c+3]);
        }
      unsigned ex[2][2][2];
#pragma unroll
      for (int kvt = 0; kvt < 2; ++kvt)
#pragma unroll
        for (int s = 0; s < 2; ++s)
#pragma unroll
          for (int wd = 0; wd < 2; ++wd) {
            unsigned snd = hi ? own[kvt][2*s][wd] : own[kvt][2*s+1][wd];
            ex[kvt][s][wd] = (unsigned)__shfl_xor((int)snd, 32);
          }
      // ---- build P^T B-frags (4 k-slices of 16 kv) ----
      bf16x8 pb[4];
#pragma unroll
      for (int ks = 0; ks < 4; ++ks) {
        int kvt = ks >> 1, s = ks & 1;
        unsigned L0 = hi ? ex[kvt][s][0]      : own[kvt][2*s][0];
        unsigned L1 = hi ? ex[kvt][s][1]      : own[kvt][2*s][1];
        unsigned H0 = hi ? own[kvt][2*s+1][0] : ex[kvt][s][0];
        unsigned H1 = hi ? own[kvt][2*s+1][1] : ex[kvt][s][1];
        uint4 u = {L0, L1, H0, H1};
        pb[ks] = as_bf16x8(u);
      }
      // ---- O^T += V^T @ P^T ----
#pragma unroll
      for (int dt = 0; dt < 2; ++dt) {
        int d = dt*32 + q31;
#pragma unroll
        for (int ks = 0; ks < 4; ++ks) {
          int phys = (2*ks + hi) ^ (d & 7);
          bf16x8 va = as_bf16x8(*(const uint4*)(Vsb + d*64 + phys*8));
          oacc[dt] = __builtin_amdgcn_mfma_f32_32x32x16_bf16(va, pb[ks], oacc[dt], 0, 0, 0);
        }
      }
    }
    cur ^= 1;
  }
  // ---- epilogue: O^T/l -> per-wave LDS [32 q][64 d] (swizzled) -> coalesced ao
  float inv = 1.0f / l;
  u16* ep = &lds[0][0][0] + w*2048;     // buf0 free: T even, last prefetch went to buf1
#pragma unroll
  for (int dt = 0; dt < 2; ++dt)
#pragma unroll
    for (int c = 0; c < 4; ++c) {
      unsigned w0 = cvtpk(oacc[dt][4*c+0]*inv, oacc[dt][4*c+1]*inv);
      unsigned w1 = cvtpk(oacc[dt][4*c+2]*inv, oacc[dt][4*c+3]*inv);
      int colb = dt*64 + c*16 + hi*8;   // byte col of d-base
      int addrb = q31*128 + (colb ^ ((q31 & 7) << 4));
      *(uint2*)((char*)ep + addrb) = make_uint2(w0, w1);
    }
#pragma unroll
  for (int it = 0; it < 4; ++it) {
    int r  = (lane >> 3) + 8*it;
    int c8 = lane & 7;
    int phys = (c8*16) ^ ((r & 7) << 4);
    uint4 vv = *(const uint4*)((const char*)ep + r*128 + phys);
    *(uint4*)(ao + ((size_t)b*NS + q0 + w*32 + r)*(size_t)(NHEAD*DHEAD) + h*DHEAD + c8*8) = vv;
  }
}

// ---------------- launch -----------------------------------------------------
// Workspace (63 MB, lifetime-aliased):
//   [0,16M)       hb (bf16 hidden)  -> reused as qr
//   [16M,29.4M)   wqkv              -> reused as kr (4M) + vt (4M @20.97M)
//   [29.4M,54.5M) qkv               -> reused as ao
//   [54.5M,62.9M) wob
extern "C" void kernel_launch(void* const* d_in, const int* in_sizes, int n_in,
                              void* d_out, int out_size, void* d_ws, size_t ws_size,
                              hipStream_t stream) {
  const float* hs   = (const float*)d_in[0];
  const float* cosb = (const float*)d_in[1];
  const float* sinb = (const float*)d_in[2];
  // d_in[3] = attention_mask: exactly causal -> applied analytically, never read
  const float* Wq = (const float*)d_in[4];
  const float* Wk = (const float*)d_in[5];
  const float* Wv = (const float*)d_in[6];
  const float* Wo = (const float*)d_in[7];
  char* ws = (char*)d_ws;
  u16* hb   = (u16*)(ws);
  u16* wqkv = (u16*)(ws + 16777216);
  u16* qkv  = (u16*)(ws + 29360128);
  u16* wob  = (u16*)(ws + 54525952);
  u16* qrb  = hb;
  u16* krb  = wqkv;
  u16* vtb  = (u16*)(ws + 20971520);
  u16* aob  = qkv;

  cast_f32_to_bf16<<<4096, 256, 0, stream>>>(hs, hb, 1048576);
  cast_f32_to_bf16<<<2048, 256, 0, stream>>>(Wq, wqkv, 524288);
  cast_f32_to_bf16<<< 512, 256, 0, stream>>>(Wk, wqkv + 2048*2048, 131072);
  cast_f32_to_bf16<<< 512, 256, 0, stream>>>(Wv, wqkv + 2560*2048, 131072);
  cast_f32_to_bf16<<<2048, 256, 0, stream>>>(Wo, wob, 524288);

  gemm_bt<0><<<(NQKV/128)*(MROWS/128), 256, 0, stream>>>(hb, wqkv, qkv, MROWS, NQKV, NHID, NQKV/128);
  rope_qk<<<MROWS, 256, 0, stream>>>(qkv, cosb, sinb, qrb, krb);
  v_trans<<<512, 256, 0, stream>>>(qkv, vtb);
  attn_fwd<<<1024, 256, 0, stream>>>(qrb, krb, vtb, aob);
  gemm_bt<1><<<(NHID/128)*(MROWS/128), 256, 0, stream>>>(aob, wob, d_out, MROWS, NHID, NHEAD*DHEAD, NHID/128);
}